// Round 3
// baseline (666.421 us; speedup 1.0000x reference)
//
#include <hip/hip_runtime.h>

// ---------------------------------------------------------------------------
// GCN 6-layer forward on MI355X.
// Pipeline per call (all on `stream`, graph-capture safe):
//   1. deg histogram over dst  (+1 self loop folded into inv computation)
//   2. inv[v] = rsqrt(deg[v]+1)
//   3. prefix-sum deg -> row_ptr (3-kernel scan), cursor = copy(row_ptr)
//   4. counting-sort edges by dst -> col[] (CSR, values = src ids)
//   5. gstart[g] = lower_bound(batch, g)  (batch is sorted)
//   6. per layer: hs = inv .* (h @ W)   [tiled fp32 GEMM, VALU]
//                 h' = act(inv .* (sum_{e in row} hs[col[e]] + hs[v]) + b)
//   7. segment-mean pool over gstart ranges, final 128x32 linear
// ---------------------------------------------------------------------------

static inline int ceil_div(int a, int b) { return (a + b - 1) / b; }

// ---------------- setup kernels ----------------

__global__ __launch_bounds__(256) void hist_i32(const int* __restrict__ idx,
                                                int* __restrict__ cnt, int n) {
  int i = blockIdx.x * 256 + threadIdx.x;
  if (i < n) atomicAdd(&cnt[idx[i]], 1);
}

__global__ __launch_bounds__(256) void inv_sqrt_deg(const int* __restrict__ deg,
                                                    float* __restrict__ inv, int n) {
  int i = blockIdx.x * 256 + threadIdx.x;
  if (i < n) inv[i] = rsqrtf((float)(deg[i] + 1));  // +1 = self loop
}

// inclusive scan, chunk = 256
__global__ __launch_bounds__(256) void scanA(const int* __restrict__ deg,
                                             int* __restrict__ tmp,
                                             int* __restrict__ sums, int n) {
  __shared__ int s[256];
  int t = threadIdx.x;
  int gid = blockIdx.x * 256 + t;
  s[t] = (gid < n) ? deg[gid] : 0;
  __syncthreads();
  for (int off = 1; off < 256; off <<= 1) {
    int add = (t >= off) ? s[t - off] : 0;
    __syncthreads();
    s[t] += add;
    __syncthreads();
  }
  if (gid < n) tmp[gid] = s[t];
  if (t == 255) sums[blockIdx.x] = s[255];
}

__global__ __launch_bounds__(256) void scanB(int* __restrict__ sums, int nchunk) {
  __shared__ int s[256];
  int t = threadIdx.x;
  s[t] = (t < nchunk) ? sums[t] : 0;
  __syncthreads();
  for (int off = 1; off < 256; off <<= 1) {
    int add = (t >= off) ? s[t - off] : 0;
    __syncthreads();
    s[t] += add;
    __syncthreads();
  }
  if (t < nchunk) sums[t] = s[t];
}

__global__ __launch_bounds__(256) void scanC(const int* __restrict__ tmp,
                                             const int* __restrict__ sums,
                                             int* __restrict__ rp, int n) {
  int gid = blockIdx.x * 256 + threadIdx.x;
  if (gid < n) {
    int off = (blockIdx.x > 0) ? sums[blockIdx.x - 1] : 0;
    rp[gid + 1] = tmp[gid] + off;
    if (gid == 0) rp[0] = 0;
  }
}

// gstart[g] = first i with batch[i] >= g  (batch sorted ascending)
__global__ __launch_bounds__(256) void bsearch_starts(const int* __restrict__ batch,
                                                      int* __restrict__ gstart,
                                                      int n, int B) {
  int g = blockIdx.x * 256 + threadIdx.x;
  if (g > B) return;
  int lo = 0, hi = n;
  while (lo < hi) {
    int mid = (lo + hi) >> 1;
    if (batch[mid] < g) lo = mid + 1; else hi = mid;
  }
  gstart[g] = lo;
}

__global__ __launch_bounds__(256) void scatter_edges(const int* __restrict__ src,
                                                     const int* __restrict__ dst,
                                                     int* __restrict__ cursor,
                                                     int* __restrict__ col, int E) {
  int i = blockIdx.x * 256 + threadIdx.x;
  if (i < E) {
    int d = dst[i];
    int pos = atomicAdd(&cursor[d], 1);
    col[pos] = src[i];
  }
}

// ---------------- per-layer kernels ----------------

// hs[v][c] = inv[v] * sum_k A[v][k] * W[k][c]
// block = 256 threads, tile 64 rows x 128 cols, K-step 32.
// A staged TRANSPOSED As_t[k][row] (row stride 68 floats = 272B, 16B-aligned
// float4 reads; inner loop = 1 b128 A-read + 2 b128 W-reads per k).
__global__ __launch_bounds__(256) void gemm_scale(const float* __restrict__ A,
                                                  const float* __restrict__ W,
                                                  const float* __restrict__ inv,
                                                  float* __restrict__ out, int nrows) {
  __shared__ float As_t[32][68];
  __shared__ float Ws[32][128];
  int t = threadIdx.x;
  int tx = t & 15;   // 16 col-groups
  int ty = t >> 4;   // 16 row-groups
  int rowBase = blockIdx.x * 64;

  float acc[4][8];
#pragma unroll
  for (int i = 0; i < 4; ++i)
#pragma unroll
    for (int j = 0; j < 8; ++j) acc[i][j] = 0.f;

  for (int k0 = 0; k0 < 128; k0 += 32) {
    // stage A (transposed): thread r=t>>3 (0..31), kv=(t&7)*4, two row-passes
    {
      int r = t >> 3;
      int kv = (t & 7) * 4;
#pragma unroll
      for (int p = 0; p < 2; ++p) {
        int rr = r + p * 32;
        int gr = rowBase + rr;
        int grc = (gr < nrows) ? gr : (nrows - 1);
        const float4 av = *(const float4*)&A[(size_t)grc * 128 + k0 + kv];
        As_t[kv + 0][rr] = av.x;
        As_t[kv + 1][rr] = av.y;
        As_t[kv + 2][rr] = av.z;
        As_t[kv + 3][rr] = av.w;
      }
      // stage W: 32 k x 128 c, 4 passes of 256 float4
#pragma unroll
      for (int p = 0; p < 4; ++p) {
        int idx = p * 1024 + t * 4;
        int kr = idx >> 7;
        int cc = idx & 127;
        *(float4*)&Ws[kr][cc] = *(const float4*)&W[(size_t)(k0 + kr) * 128 + cc];
      }
    }
    __syncthreads();

#pragma unroll 8
    for (int k = 0; k < 32; ++k) {
      float4 a = *(const float4*)&As_t[k][ty * 4];
      float4 w0 = *(const float4*)&Ws[k][tx * 4];
      float4 w1 = *(const float4*)&Ws[k][64 + tx * 4];
      float ar[4] = {a.x, a.y, a.z, a.w};
      float wr[8] = {w0.x, w0.y, w0.z, w0.w, w1.x, w1.y, w1.z, w1.w};
#pragma unroll
      for (int i = 0; i < 4; ++i)
#pragma unroll
        for (int j = 0; j < 8; ++j) acc[i][j] += ar[i] * wr[j];
    }
    __syncthreads();
  }

#pragma unroll
  for (int i = 0; i < 4; ++i) {
    int gr = rowBase + ty * 4 + i;
    if (gr < nrows) {
      float iv = inv[gr];
      float4 o0 = make_float4(acc[i][0] * iv, acc[i][1] * iv, acc[i][2] * iv, acc[i][3] * iv);
      float4 o1 = make_float4(acc[i][4] * iv, acc[i][5] * iv, acc[i][6] * iv, acc[i][7] * iv);
      *(float4*)&out[(size_t)gr * 128 + tx * 4] = o0;
      *(float4*)&out[(size_t)gr * 128 + 64 + tx * 4] = o1;
    }
  }
}

// out[v][:] = act(inv[v] * (sum_{e in row v} hs[col[e]][:] + hs[v][:]) + b)
// one 64-lane wave per node, float2 per lane, 8-deep gather pipeline
// (8 independent accumulator pairs => 8 outstanding 512B gathers/wave).
__global__ __launch_bounds__(256) void aggregate(const float* __restrict__ hs,
                                                 const int* __restrict__ col,
                                                 const int* __restrict__ rp,
                                                 const float* __restrict__ inv,
                                                 const float* __restrict__ bias,
                                                 float* __restrict__ out, int n,
                                                 int dorelu) {
  int node = blockIdx.x * 4 + (threadIdx.x >> 6);
  if (node >= n) return;
  int lane = threadIdx.x & 63;
  const float2* h2 = (const float2*)hs;

  int beg = rp[node], end = rp[node + 1];
  float2 self = h2[(size_t)node * 64 + lane];
  float sx[8], sy[8];
  sx[0] = self.x; sy[0] = self.y;
#pragma unroll
  for (int i = 1; i < 8; ++i) { sx[i] = 0.f; sy[i] = 0.f; }

  int e = beg;
  for (; e + 8 <= end; e += 8) {
    int idx[8];
#pragma unroll
    for (int i = 0; i < 8; ++i) idx[i] = col[e + i];
    float2 v[8];
#pragma unroll
    for (int i = 0; i < 8; ++i) v[i] = h2[(size_t)idx[i] * 64 + lane];
#pragma unroll
    for (int i = 0; i < 8; ++i) { sx[i] += v[i].x; sy[i] += v[i].y; }
  }
  if (e + 4 <= end) {
    int idx[4];
#pragma unroll
    for (int i = 0; i < 4; ++i) idx[i] = col[e + i];
    float2 v[4];
#pragma unroll
    for (int i = 0; i < 4; ++i) v[i] = h2[(size_t)idx[i] * 64 + lane];
#pragma unroll
    for (int i = 0; i < 4; ++i) { sx[i] += v[i].x; sy[i] += v[i].y; }
    e += 4;
  }
  for (; e < end; ++e) {
    int s = col[e];
    float2 v = h2[(size_t)s * 64 + lane];
    sx[0] += v.x; sy[0] += v.y;
  }

  float ax = (sx[0] + sx[1]) + (sx[2] + sx[3]);
  float bx = (sx[4] + sx[5]) + (sx[6] + sx[7]);
  float ay = (sy[0] + sy[1]) + (sy[2] + sy[3]);
  float by = (sy[4] + sy[5]) + (sy[6] + sy[7]);

  float iv = inv[node];
  float rx = iv * (ax + bx) + bias[lane * 2 + 0];
  float ry = iv * (ay + by) + bias[lane * 2 + 1];
  if (dorelu) { rx = fmaxf(rx, 0.f); ry = fmaxf(ry, 0.f); }
  ((float2*)out)[(size_t)node * 64 + lane] = make_float2(rx, ry);
}

// segment-mean pool: one block (128 threads) per graph, ranges from gstart
__global__ __launch_bounds__(128) void pool_mean(const float* __restrict__ h,
                                                 const int* __restrict__ gstart,
                                                 float* __restrict__ pooled) {
  int g = blockIdx.x;
  int c = threadIdx.x;
  int s = gstart[g], e = gstart[g + 1];
  float acc = 0.f;
  for (int v = s; v < e; ++v) acc += h[(size_t)v * 128 + c];
  int cnt = e - s;
  pooled[(size_t)g * 128 + c] = acc / (float)(cnt > 0 ? cnt : 1);
}

// out[g][c] = sum_k pooled[g][k] * lin_W[k][c] + lin_b[c]   (512x32 outputs)
__global__ __launch_bounds__(256) void final_lin(const float* __restrict__ pooled,
                                                 const float* __restrict__ lw,
                                                 const float* __restrict__ lb,
                                                 float* __restrict__ out, int total) {
  int idx = blockIdx.x * 256 + threadIdx.x;
  if (idx >= total) return;
  int g = idx >> 5;
  int c = idx & 31;
  float s = 0.f;
#pragma unroll 8
  for (int k = 0; k < 128; ++k) s += pooled[(size_t)g * 128 + k] * lw[k * 32 + c];
  out[idx] = s + lb[c];
}

// ---------------- launch ----------------

extern "C" void kernel_launch(void* const* d_in, const int* in_sizes, int n_in,
                              void* d_out, int out_size, void* d_ws, size_t ws_size,
                              hipStream_t stream) {
  const float* x = (const float*)d_in[0];
  const int* ei = (const int*)d_in[1];
  const int* batch = (const int*)d_in[2];
  const float* W[6];
  const float* bvec[6];
  for (int i = 0; i < 6; ++i) {
    W[i] = (const float*)d_in[3 + 2 * i];
    bvec[i] = (const float*)d_in[4 + 2 * i];
  }
  const float* linW = (const float*)d_in[15];
  const float* linb = (const float*)d_in[16];
  float* out = (float*)d_out;

  const int F = 128, H = 128, C = 32;
  const int N = in_sizes[0] / F;
  const int E = in_sizes[1] / 2;
  const int B = out_size / C;  // 512
  const int* src = ei;
  const int* dst = ei + E;

  // workspace carve-out (256B aligned slices)
  char* w = (char*)d_ws;
  auto alloc = [&](size_t bytes) -> char* {
    char* p = w;
    w += (bytes + 255) & ~(size_t)255;
    return p;
  };
  int* deg = (int*)alloc((size_t)N * 4);
  float* inv = (float*)alloc((size_t)N * 4);
  int* tmp = (int*)alloc((size_t)N * 4);
  int* sums = (int*)alloc(256 * 4);
  int* rp = (int*)alloc((size_t)(N + 1) * 4);
  int* cursor = (int*)alloc((size_t)N * 4);
  int* col = (int*)alloc((size_t)E * 4);
  int* gstart = (int*)alloc((size_t)(B + 1) * 4);
  float* bufA = (float*)alloc((size_t)N * H * 4);
  float* bufB = (float*)alloc((size_t)N * H * 4);
  float* pooled = (float*)alloc((size_t)B * H * 4);
  (void)n_in; (void)ws_size;

  hipMemsetAsync(deg, 0, (size_t)N * 4, stream);

  hist_i32<<<ceil_div(E, 256), 256, 0, stream>>>(dst, deg, E);
  inv_sqrt_deg<<<ceil_div(N, 256), 256, 0, stream>>>(deg, inv, N);

  int nchunk = ceil_div(N, 256);  // 196 for N=50000, fits scanB's 256 slots
  scanA<<<nchunk, 256, 0, stream>>>(deg, tmp, sums, N);
  scanB<<<1, 256, 0, stream>>>(sums, nchunk);
  scanC<<<nchunk, 256, 0, stream>>>(tmp, sums, rp, N);
  bsearch_starts<<<ceil_div(B + 1, 256), 256, 0, stream>>>(batch, gstart, N, B);

  hipMemcpyAsync(cursor, rp, (size_t)N * 4, hipMemcpyDeviceToDevice, stream);
  scatter_edges<<<ceil_div(E, 256), 256, 0, stream>>>(src, dst, cursor, col, E);

  const float* hin = x;
  for (int l = 0; l < 6; ++l) {
    gemm_scale<<<ceil_div(N, 64), 256, 0, stream>>>(hin, W[l], inv, bufB, N);
    aggregate<<<ceil_div(N, 4), 256, 0, stream>>>(bufB, col, rp, inv, bvec[l], bufA, N,
                                                  (l < 5) ? 1 : 0);
    hin = bufA;
  }

  pool_mean<<<B, 128, 0, stream>>>(bufA, gstart, pooled);
  final_lin<<<ceil_div(B * C, 256), 256, 0, stream>>>(pooled, linW, linb, out, B * C);
}

// Round 4
// 568.108 us; speedup vs baseline: 1.1731x; 1.1731x over previous
//
#include <hip/hip_runtime.h>
#include <hip/hip_fp16.h>

// ---------------------------------------------------------------------------
// GCN 6-layer forward on MI355X.
// Pipeline per call (all on `stream`, graph-capture safe):
//   1. deg histogram over dst  (+1 self loop folded into inv computation)
//   2. inv[v] = rsqrt(deg[v]+1)
//   3. prefix-sum deg -> row_ptr (3-kernel scan), cursor = copy(row_ptr)
//   4. counting-sort edges by dst -> col[] (CSR, values = src ids)
//   5. gstart[g] = lower_bound(batch, g)  (batch is sorted)
//   6. per layer: hs16 = fp16(inv .* (h @ W))   [tiled fp32 GEMM, VALU]
//                 h' = act(inv .* (sum_{e in row} hs16[col[e]] + hs16[v]) + b)
//        (fp16 gather buffer halves the L2-miss traffic that bounds aggregate;
//         accumulation stays fp32)
//   7. segment-mean pool over gstart ranges, final 128x32 linear
// ---------------------------------------------------------------------------

static inline int ceil_div(int a, int b) { return (a + b - 1) / b; }

// ---------------- setup kernels ----------------

__global__ __launch_bounds__(256) void hist_i32(const int* __restrict__ idx,
                                                int* __restrict__ cnt, int n) {
  int i = blockIdx.x * 256 + threadIdx.x;
  if (i < n) atomicAdd(&cnt[idx[i]], 1);
}

__global__ __launch_bounds__(256) void inv_sqrt_deg(const int* __restrict__ deg,
                                                    float* __restrict__ inv, int n) {
  int i = blockIdx.x * 256 + threadIdx.x;
  if (i < n) inv[i] = rsqrtf((float)(deg[i] + 1));  // +1 = self loop
}

// inclusive scan, chunk = 256
__global__ __launch_bounds__(256) void scanA(const int* __restrict__ deg,
                                             int* __restrict__ tmp,
                                             int* __restrict__ sums, int n) {
  __shared__ int s[256];
  int t = threadIdx.x;
  int gid = blockIdx.x * 256 + t;
  s[t] = (gid < n) ? deg[gid] : 0;
  __syncthreads();
  for (int off = 1; off < 256; off <<= 1) {
    int add = (t >= off) ? s[t - off] : 0;
    __syncthreads();
    s[t] += add;
    __syncthreads();
  }
  if (gid < n) tmp[gid] = s[t];
  if (t == 255) sums[blockIdx.x] = s[255];
}

__global__ __launch_bounds__(256) void scanB(int* __restrict__ sums, int nchunk) {
  __shared__ int s[256];
  int t = threadIdx.x;
  s[t] = (t < nchunk) ? sums[t] : 0;
  __syncthreads();
  for (int off = 1; off < 256; off <<= 1) {
    int add = (t >= off) ? s[t - off] : 0;
    __syncthreads();
    s[t] += add;
    __syncthreads();
  }
  if (t < nchunk) sums[t] = s[t];
}

__global__ __launch_bounds__(256) void scanC(const int* __restrict__ tmp,
                                             const int* __restrict__ sums,
                                             int* __restrict__ rp, int n) {
  int gid = blockIdx.x * 256 + threadIdx.x;
  if (gid < n) {
    int off = (blockIdx.x > 0) ? sums[blockIdx.x - 1] : 0;
    rp[gid + 1] = tmp[gid] + off;
    if (gid == 0) rp[0] = 0;
  }
}

// gstart[g] = first i with batch[i] >= g  (batch sorted ascending)
__global__ __launch_bounds__(256) void bsearch_starts(const int* __restrict__ batch,
                                                      int* __restrict__ gstart,
                                                      int n, int B) {
  int g = blockIdx.x * 256 + threadIdx.x;
  if (g > B) return;
  int lo = 0, hi = n;
  while (lo < hi) {
    int mid = (lo + hi) >> 1;
    if (batch[mid] < g) lo = mid + 1; else hi = mid;
  }
  gstart[g] = lo;
}

__global__ __launch_bounds__(256) void scatter_edges(const int* __restrict__ src,
                                                     const int* __restrict__ dst,
                                                     int* __restrict__ cursor,
                                                     int* __restrict__ col, int E) {
  int i = blockIdx.x * 256 + threadIdx.x;
  if (i < E) {
    int d = dst[i];
    int pos = atomicAdd(&cursor[d], 1);
    col[pos] = src[i];
  }
}

// ---------------- per-layer kernels ----------------

// hs16[v][c] = fp16( inv[v] * sum_k A[v][k] * W[k][c] )
// block = 256 threads, tile 64 rows x 128 cols, K-step 32.
// A staged TRANSPOSED As_t[k][row] (row stride 68 floats = 272B, 16B-aligned
// float4 reads; inner loop = 1 b128 A-read + 2 b128 W-reads per k).
__global__ __launch_bounds__(256) void gemm_scale(const float* __restrict__ A,
                                                  const float* __restrict__ W,
                                                  const float* __restrict__ inv,
                                                  __half* __restrict__ out, int nrows) {
  __shared__ float As_t[32][68];
  __shared__ float Ws[32][128];
  int t = threadIdx.x;
  int tx = t & 15;   // 16 col-groups
  int ty = t >> 4;   // 16 row-groups
  int rowBase = blockIdx.x * 64;

  float acc[4][8];
#pragma unroll
  for (int i = 0; i < 4; ++i)
#pragma unroll
    for (int j = 0; j < 8; ++j) acc[i][j] = 0.f;

  for (int k0 = 0; k0 < 128; k0 += 32) {
    // stage A (transposed): thread r=t>>3 (0..31), kv=(t&7)*4, two row-passes
    {
      int r = t >> 3;
      int kv = (t & 7) * 4;
#pragma unroll
      for (int p = 0; p < 2; ++p) {
        int rr = r + p * 32;
        int gr = rowBase + rr;
        int grc = (gr < nrows) ? gr : (nrows - 1);
        const float4 av = *(const float4*)&A[(size_t)grc * 128 + k0 + kv];
        As_t[kv + 0][rr] = av.x;
        As_t[kv + 1][rr] = av.y;
        As_t[kv + 2][rr] = av.z;
        As_t[kv + 3][rr] = av.w;
      }
      // stage W: 32 k x 128 c, 4 passes of 256 float4
#pragma unroll
      for (int p = 0; p < 4; ++p) {
        int idx = p * 1024 + t * 4;
        int kr = idx >> 7;
        int cc = idx & 127;
        *(float4*)&Ws[kr][cc] = *(const float4*)&W[(size_t)(k0 + kr) * 128 + cc];
      }
    }
    __syncthreads();

#pragma unroll 8
    for (int k = 0; k < 32; ++k) {
      float4 a = *(const float4*)&As_t[k][ty * 4];
      float4 w0 = *(const float4*)&Ws[k][tx * 4];
      float4 w1 = *(const float4*)&Ws[k][64 + tx * 4];
      float ar[4] = {a.x, a.y, a.z, a.w};
      float wr[8] = {w0.x, w0.y, w0.z, w0.w, w1.x, w1.y, w1.z, w1.w};
#pragma unroll
      for (int i = 0; i < 4; ++i)
#pragma unroll
        for (int j = 0; j < 8; ++j) acc[i][j] += ar[i] * wr[j];
    }
    __syncthreads();
  }

#pragma unroll
  for (int i = 0; i < 4; ++i) {
    int gr = rowBase + ty * 4 + i;
    if (gr < nrows) {
      float iv = inv[gr];
      __half2 p0 = __floats2half2_rn(acc[i][0] * iv, acc[i][1] * iv);
      __half2 p1 = __floats2half2_rn(acc[i][2] * iv, acc[i][3] * iv);
      __half2 p2 = __floats2half2_rn(acc[i][4] * iv, acc[i][5] * iv);
      __half2 p3 = __floats2half2_rn(acc[i][6] * iv, acc[i][7] * iv);
      uint2 s0, s1;
      s0.x = *(unsigned*)&p0; s0.y = *(unsigned*)&p1;
      s1.x = *(unsigned*)&p2; s1.y = *(unsigned*)&p3;
      *(uint2*)&out[(size_t)gr * 128 + tx * 4] = s0;
      *(uint2*)&out[(size_t)gr * 128 + 64 + tx * 4] = s1;
    }
  }
}

// out[v][:] = act(inv[v] * (sum_{e in row v} hs16[col[e]][:] + hs16[v][:]) + b)
// one 64-lane wave per node, half2 (4B) per lane, 8-deep gather pipeline.
// fp16 rows are 256B -> 4 cache lines per gather (halved vs fp32).
__global__ __launch_bounds__(256) void aggregate(const __half* __restrict__ hs,
                                                 const int* __restrict__ col,
                                                 const int* __restrict__ rp,
                                                 const float* __restrict__ inv,
                                                 const float* __restrict__ bias,
                                                 float* __restrict__ out, int n,
                                                 int dorelu) {
  int node = blockIdx.x * 4 + (threadIdx.x >> 6);
  if (node >= n) return;
  int lane = threadIdx.x & 63;
  const __half2* h2 = (const __half2*)hs;

  int beg = rp[node], end = rp[node + 1];
  float2 self = __half22float2(h2[(size_t)node * 64 + lane]);
  float sx[8], sy[8];
  sx[0] = self.x; sy[0] = self.y;
#pragma unroll
  for (int i = 1; i < 8; ++i) { sx[i] = 0.f; sy[i] = 0.f; }

  int e = beg;
  for (; e + 8 <= end; e += 8) {
    int idx[8];
#pragma unroll
    for (int i = 0; i < 8; ++i) idx[i] = col[e + i];
    __half2 v[8];
#pragma unroll
    for (int i = 0; i < 8; ++i) v[i] = h2[(size_t)idx[i] * 64 + lane];
#pragma unroll
    for (int i = 0; i < 8; ++i) {
      float2 f = __half22float2(v[i]);
      sx[i] += f.x; sy[i] += f.y;
    }
  }
  if (e + 4 <= end) {
    int idx[4];
#pragma unroll
    for (int i = 0; i < 4; ++i) idx[i] = col[e + i];
    __half2 v[4];
#pragma unroll
    for (int i = 0; i < 4; ++i) v[i] = h2[(size_t)idx[i] * 64 + lane];
#pragma unroll
    for (int i = 0; i < 4; ++i) {
      float2 f = __half22float2(v[i]);
      sx[i] += f.x; sy[i] += f.y;
    }
    e += 4;
  }
  for (; e < end; ++e) {
    int s = col[e];
    float2 f = __half22float2(h2[(size_t)s * 64 + lane]);
    sx[0] += f.x; sy[0] += f.y;
  }

  float ax = (sx[0] + sx[1]) + (sx[2] + sx[3]);
  float bx = (sx[4] + sx[5]) + (sx[6] + sx[7]);
  float ay = (sy[0] + sy[1]) + (sy[2] + sy[3]);
  float by = (sy[4] + sy[5]) + (sy[6] + sy[7]);

  float iv = inv[node];
  float rx = iv * (ax + bx) + bias[lane * 2 + 0];
  float ry = iv * (ay + by) + bias[lane * 2 + 1];
  if (dorelu) { rx = fmaxf(rx, 0.f); ry = fmaxf(ry, 0.f); }
  ((float2*)out)[(size_t)node * 64 + lane] = make_float2(rx, ry);
}

// segment-mean pool: one block (128 threads) per graph, ranges from gstart
__global__ __launch_bounds__(128) void pool_mean(const float* __restrict__ h,
                                                 const int* __restrict__ gstart,
                                                 float* __restrict__ pooled) {
  int g = blockIdx.x;
  int c = threadIdx.x;
  int s = gstart[g], e = gstart[g + 1];
  float acc = 0.f;
  for (int v = s; v < e; ++v) acc += h[(size_t)v * 128 + c];
  int cnt = e - s;
  pooled[(size_t)g * 128 + c] = acc / (float)(cnt > 0 ? cnt : 1);
}

// out[g][c] = sum_k pooled[g][k] * lin_W[k][c] + lin_b[c]   (512x32 outputs)
__global__ __launch_bounds__(256) void final_lin(const float* __restrict__ pooled,
                                                 const float* __restrict__ lw,
                                                 const float* __restrict__ lb,
                                                 float* __restrict__ out, int total) {
  int idx = blockIdx.x * 256 + threadIdx.x;
  if (idx >= total) return;
  int g = idx >> 5;
  int c = idx & 31;
  float s = 0.f;
#pragma unroll 8
  for (int k = 0; k < 128; ++k) s += pooled[(size_t)g * 128 + k] * lw[k * 32 + c];
  out[idx] = s + lb[c];
}

// ---------------- launch ----------------

extern "C" void kernel_launch(void* const* d_in, const int* in_sizes, int n_in,
                              void* d_out, int out_size, void* d_ws, size_t ws_size,
                              hipStream_t stream) {
  const float* x = (const float*)d_in[0];
  const int* ei = (const int*)d_in[1];
  const int* batch = (const int*)d_in[2];
  const float* W[6];
  const float* bvec[6];
  for (int i = 0; i < 6; ++i) {
    W[i] = (const float*)d_in[3 + 2 * i];
    bvec[i] = (const float*)d_in[4 + 2 * i];
  }
  const float* linW = (const float*)d_in[15];
  const float* linb = (const float*)d_in[16];
  float* out = (float*)d_out;

  const int F = 128, H = 128, C = 32;
  const int N = in_sizes[0] / F;
  const int E = in_sizes[1] / 2;
  const int B = out_size / C;  // 512
  const int* src = ei;
  const int* dst = ei + E;

  // workspace carve-out (256B aligned slices)
  char* w = (char*)d_ws;
  auto alloc = [&](size_t bytes) -> char* {
    char* p = w;
    w += (bytes + 255) & ~(size_t)255;
    return p;
  };
  int* deg = (int*)alloc((size_t)N * 4);
  float* inv = (float*)alloc((size_t)N * 4);
  int* tmp = (int*)alloc((size_t)N * 4);
  int* sums = (int*)alloc(256 * 4);
  int* rp = (int*)alloc((size_t)(N + 1) * 4);
  int* cursor = (int*)alloc((size_t)N * 4);
  int* col = (int*)alloc((size_t)E * 4);
  int* gstart = (int*)alloc((size_t)(B + 1) * 4);
  float* bufA = (float*)alloc((size_t)N * H * 4);
  __half* hs16 = (__half*)alloc((size_t)N * H * 2);
  float* pooled = (float*)alloc((size_t)B * H * 4);
  (void)n_in; (void)ws_size;

  hipMemsetAsync(deg, 0, (size_t)N * 4, stream);

  hist_i32<<<ceil_div(E, 256), 256, 0, stream>>>(dst, deg, E);
  inv_sqrt_deg<<<ceil_div(N, 256), 256, 0, stream>>>(deg, inv, N);

  int nchunk = ceil_div(N, 256);  // 196 for N=50000, fits scanB's 256 slots
  scanA<<<nchunk, 256, 0, stream>>>(deg, tmp, sums, N);
  scanB<<<1, 256, 0, stream>>>(sums, nchunk);
  scanC<<<nchunk, 256, 0, stream>>>(tmp, sums, rp, N);
  bsearch_starts<<<ceil_div(B + 1, 256), 256, 0, stream>>>(batch, gstart, N, B);

  hipMemcpyAsync(cursor, rp, (size_t)N * 4, hipMemcpyDeviceToDevice, stream);
  scatter_edges<<<ceil_div(E, 256), 256, 0, stream>>>(src, dst, cursor, col, E);

  const float* hin = x;
  for (int l = 0; l < 6; ++l) {
    gemm_scale<<<ceil_div(N, 64), 256, 0, stream>>>(hin, W[l], inv, hs16, N);
    aggregate<<<ceil_div(N, 4), 256, 0, stream>>>(hs16, col, rp, inv, bvec[l], bufA, N,
                                                  (l < 5) ? 1 : 0);
    hin = bufA;
  }

  pool_mean<<<B, 128, 0, stream>>>(bufA, gstart, pooled);
  final_lin<<<ceil_div(B * C, 256), 256, 0, stream>>>(pooled, linW, linb, out, B * C);
}

// Round 5
// 535.119 us; speedup vs baseline: 1.2454x; 1.0616x over previous
//
#include <hip/hip_runtime.h>
#include <hip/hip_fp16.h>

// ---------------------------------------------------------------------------
// GCN 6-layer forward on MI355X — fp16 state + MFMA transform.
//   setup: deg/inv, row_ptr scan, counting-sort CSR, batch bsearch,
//          x -> fp16, W(6) -> fp16 transposed Wt[c][k]
//   per layer: hs16 = fp16(inv .* (h16 @ W))  [v_mfma_f32_16x16x32_f16]
//              h16  = fp16(act(inv .* (sum_e hs16[col[e]] + hs16[v]) + b))
//   pool (fp16 in, fp32 acc) -> final 128x32 linear (fp32)
// ---------------------------------------------------------------------------

static inline int ceil_div(int a, int b) { return (a + b - 1) / b; }

typedef _Float16 f16x8 __attribute__((ext_vector_type(8)));
typedef _Float16 f16x4 __attribute__((ext_vector_type(4)));
typedef float f32x4 __attribute__((ext_vector_type(4)));

// ---------------- setup kernels ----------------

__global__ __launch_bounds__(256) void hist_i32(const int* __restrict__ idx,
                                                int* __restrict__ cnt, int n) {
  int i = blockIdx.x * 256 + threadIdx.x;
  if (i < n) atomicAdd(&cnt[idx[i]], 1);
}

__global__ __launch_bounds__(256) void inv_sqrt_deg(const int* __restrict__ deg,
                                                    float* __restrict__ inv, int n) {
  int i = blockIdx.x * 256 + threadIdx.x;
  if (i < n) inv[i] = rsqrtf((float)(deg[i] + 1));  // +1 = self loop
}

__global__ __launch_bounds__(256) void scanA(const int* __restrict__ deg,
                                             int* __restrict__ tmp,
                                             int* __restrict__ sums, int n) {
  __shared__ int s[256];
  int t = threadIdx.x;
  int gid = blockIdx.x * 256 + t;
  s[t] = (gid < n) ? deg[gid] : 0;
  __syncthreads();
  for (int off = 1; off < 256; off <<= 1) {
    int add = (t >= off) ? s[t - off] : 0;
    __syncthreads();
    s[t] += add;
    __syncthreads();
  }
  if (gid < n) tmp[gid] = s[t];
  if (t == 255) sums[blockIdx.x] = s[255];
}

__global__ __launch_bounds__(256) void scanB(int* __restrict__ sums, int nchunk) {
  __shared__ int s[256];
  int t = threadIdx.x;
  s[t] = (t < nchunk) ? sums[t] : 0;
  __syncthreads();
  for (int off = 1; off < 256; off <<= 1) {
    int add = (t >= off) ? s[t - off] : 0;
    __syncthreads();
    s[t] += add;
    __syncthreads();
  }
  if (t < nchunk) sums[t] = s[t];
}

__global__ __launch_bounds__(256) void scanC(const int* __restrict__ tmp,
                                             const int* __restrict__ sums,
                                             int* __restrict__ rp, int n) {
  int gid = blockIdx.x * 256 + threadIdx.x;
  if (gid < n) {
    int off = (blockIdx.x > 0) ? sums[blockIdx.x - 1] : 0;
    rp[gid + 1] = tmp[gid] + off;
    if (gid == 0) rp[0] = 0;
  }
}

// gstart[g] = first i with batch[i] >= g  (batch sorted ascending)
__global__ __launch_bounds__(256) void bsearch_starts(const int* __restrict__ batch,
                                                      int* __restrict__ gstart,
                                                      int n, int B) {
  int g = blockIdx.x * 256 + threadIdx.x;
  if (g > B) return;
  int lo = 0, hi = n;
  while (lo < hi) {
    int mid = (lo + hi) >> 1;
    if (batch[mid] < g) lo = mid + 1; else hi = mid;
  }
  gstart[g] = lo;
}

__global__ __launch_bounds__(256) void scatter_edges(const int* __restrict__ src,
                                                     const int* __restrict__ dst,
                                                     int* __restrict__ cursor,
                                                     int* __restrict__ col, int E) {
  int i = blockIdx.x * 256 + threadIdx.x;
  if (i < E) {
    int d = dst[i];
    int pos = atomicAdd(&cursor[d], 1);
    col[pos] = src[i];
  }
}

// x (fp32) -> fp16, 4 elems/thread; n multiple of 4
__global__ __launch_bounds__(256) void f32_to_f16(const float* __restrict__ in,
                                                  _Float16* __restrict__ out, int n) {
  int i = (blockIdx.x * 256 + threadIdx.x) * 4;
  if (i < n) {
    float4 v = *(const float4*)&in[i];
    f16x4 o = {(_Float16)v.x, (_Float16)v.y, (_Float16)v.z, (_Float16)v.w};
    *(f16x4*)&out[i] = o;
  }
}

// 6 weights 128x128: wt[wi][c][k] = (fp16) W[wi][k][c]
struct WP { const float* p[6]; };
__global__ __launch_bounds__(256) void conv_weights(WP wp, _Float16* __restrict__ wt) {
  int wi = blockIdx.x >> 6;                       // 64 blocks per weight
  int e = (blockIdx.x & 63) * 256 + threadIdx.x;  // 0..16383
  int k = e >> 7, c = e & 127;
  wt[((size_t)wi << 14) + (size_t)c * 128 + k] = (_Float16)wp.p[wi][e];
}

// ---------------- per-layer kernels ----------------

// hs16[v][c] = fp16( inv[v] * sum_k h16[v][k] * W[k][c] )
// 4 waves/block, wave = 16 rows x 128 cols. No LDS: Wt (32KB) is L1-resident,
// h rows stream once. MFMA 16x16x32 f16, fp32 accum.
// Fragment layout: A lane l -> row (l&15), k = (l>>4)*8 + [0..8)
//                  B lane l -> col (l&15), k = (l>>4)*8 + [0..8)   (from Wt[c][k])
//                  C lane l -> col (l&15), row = (l>>4)*4 + reg    (HW-verified)
__global__ __launch_bounds__(256) void gemm_mfma(const _Float16* __restrict__ A,
                                                 const _Float16* __restrict__ Wt,
                                                 const float* __restrict__ inv,
                                                 _Float16* __restrict__ out, int nrows) {
  int lane = threadIdx.x & 63;
  int wv = threadIdx.x >> 6;  // 0..3
  int rowBase = blockIdx.x * 64 + wv * 16;
  int r = lane & 15, g = lane >> 4;

  // A-fragments for the 4 K-steps
  int arow = rowBase + r;
  if (arow >= nrows) arow = nrows - 1;
  const _Float16* ap = A + (size_t)arow * 128 + g * 8;
  f16x8 a0 = *(const f16x8*)(ap + 0);
  f16x8 a1 = *(const f16x8*)(ap + 32);
  f16x8 a2 = *(const f16x8*)(ap + 64);
  f16x8 a3 = *(const f16x8*)(ap + 96);

  f32x4 acc[8];
#pragma unroll
  for (int ct = 0; ct < 8; ++ct) acc[ct] = (f32x4){0.f, 0.f, 0.f, 0.f};

  const _Float16* bp = Wt + (size_t)r * 128 + g * 8;
#pragma unroll
  for (int ct = 0; ct < 8; ++ct) {
    const _Float16* bt = bp + (size_t)ct * 16 * 128;
    f16x8 b0 = *(const f16x8*)(bt + 0);
    f16x8 b1 = *(const f16x8*)(bt + 32);
    f16x8 b2 = *(const f16x8*)(bt + 64);
    f16x8 b3 = *(const f16x8*)(bt + 96);
    acc[ct] = __builtin_amdgcn_mfma_f32_16x16x32_f16(a0, b0, acc[ct], 0, 0, 0);
    acc[ct] = __builtin_amdgcn_mfma_f32_16x16x32_f16(a1, b1, acc[ct], 0, 0, 0);
    acc[ct] = __builtin_amdgcn_mfma_f32_16x16x32_f16(a2, b2, acc[ct], 0, 0, 0);
    acc[ct] = __builtin_amdgcn_mfma_f32_16x16x32_f16(a3, b3, acc[ct], 0, 0, 0);
  }

  // epilogue: lane writes cols ct*16+r at rows rowBase + g*4 + j
#pragma unroll
  for (int j = 0; j < 4; ++j) {
    int row = rowBase + g * 4 + j;
    if (row < nrows) {
      float iv = inv[row];
#pragma unroll
      for (int ct = 0; ct < 8; ++ct)
        out[(size_t)row * 128 + ct * 16 + r] = (_Float16)(acc[ct][j] * iv);
    }
  }
}

// h16out[v][:] = fp16(act(inv[v]*(sum_e hs16[col[e]][:] + hs16[v][:]) + b))
// one 64-lane wave per node, half2 per lane, 8-deep gather pipeline.
__global__ __launch_bounds__(256) void aggregate(const __half* __restrict__ hs,
                                                 const int* __restrict__ col,
                                                 const int* __restrict__ rp,
                                                 const float* __restrict__ inv,
                                                 const float* __restrict__ bias,
                                                 __half* __restrict__ out, int n,
                                                 int dorelu) {
  int node = blockIdx.x * 4 + (threadIdx.x >> 6);
  if (node >= n) return;
  int lane = threadIdx.x & 63;
  const __half2* h2 = (const __half2*)hs;

  int beg = rp[node], end = rp[node + 1];
  float2 self = __half22float2(h2[(size_t)node * 64 + lane]);
  float sx[8], sy[8];
  sx[0] = self.x; sy[0] = self.y;
#pragma unroll
  for (int i = 1; i < 8; ++i) { sx[i] = 0.f; sy[i] = 0.f; }

  int e = beg;
  for (; e + 8 <= end; e += 8) {
    int idx[8];
#pragma unroll
    for (int i = 0; i < 8; ++i) idx[i] = col[e + i];
    __half2 v[8];
#pragma unroll
    for (int i = 0; i < 8; ++i) v[i] = h2[(size_t)idx[i] * 64 + lane];
#pragma unroll
    for (int i = 0; i < 8; ++i) {
      float2 f = __half22float2(v[i]);
      sx[i] += f.x; sy[i] += f.y;
    }
  }
  if (e + 4 <= end) {
    int idx[4];
#pragma unroll
    for (int i = 0; i < 4; ++i) idx[i] = col[e + i];
    __half2 v[4];
#pragma unroll
    for (int i = 0; i < 4; ++i) v[i] = h2[(size_t)idx[i] * 64 + lane];
#pragma unroll
    for (int i = 0; i < 4; ++i) {
      float2 f = __half22float2(v[i]);
      sx[i] += f.x; sy[i] += f.y;
    }
    e += 4;
  }
  for (; e < end; ++e) {
    int s = col[e];
    float2 f = __half22float2(h2[(size_t)s * 64 + lane]);
    sx[0] += f.x; sy[0] += f.y;
  }

  float ax = (sx[0] + sx[1]) + (sx[2] + sx[3]);
  float bx = (sx[4] + sx[5]) + (sx[6] + sx[7]);
  float ay = (sy[0] + sy[1]) + (sy[2] + sy[3]);
  float by = (sy[4] + sy[5]) + (sy[6] + sy[7]);

  float iv = inv[node];
  float rx = iv * (ax + bx) + bias[lane * 2 + 0];
  float ry = iv * (ay + by) + bias[lane * 2 + 1];
  if (dorelu) { rx = fmaxf(rx, 0.f); ry = fmaxf(ry, 0.f); }
  ((__half2*)out)[(size_t)node * 64 + lane] = __floats2half2_rn(rx, ry);
}

// segment-mean pool: one block (128 threads) per graph, fp16 in, fp32 acc
__global__ __launch_bounds__(128) void pool_mean(const __half* __restrict__ h,
                                                 const int* __restrict__ gstart,
                                                 float* __restrict__ pooled) {
  int g = blockIdx.x;
  int c = threadIdx.x;
  int s = gstart[g], e = gstart[g + 1];
  float acc = 0.f;
  for (int v = s; v < e; ++v) acc += __half2float(h[(size_t)v * 128 + c]);
  int cnt = e - s;
  pooled[(size_t)g * 128 + c] = acc / (float)(cnt > 0 ? cnt : 1);
}

// out[g][c] = sum_k pooled[g][k] * lin_W[k][c] + lin_b[c]   (512x32 outputs)
__global__ __launch_bounds__(256) void final_lin(const float* __restrict__ pooled,
                                                 const float* __restrict__ lw,
                                                 const float* __restrict__ lb,
                                                 float* __restrict__ out, int total) {
  int idx = blockIdx.x * 256 + threadIdx.x;
  if (idx >= total) return;
  int g = idx >> 5;
  int c = idx & 31;
  float s = 0.f;
#pragma unroll 8
  for (int k = 0; k < 128; ++k) s += pooled[(size_t)g * 128 + k] * lw[k * 32 + c];
  out[idx] = s + lb[c];
}

// ---------------- launch ----------------

extern "C" void kernel_launch(void* const* d_in, const int* in_sizes, int n_in,
                              void* d_out, int out_size, void* d_ws, size_t ws_size,
                              hipStream_t stream) {
  const float* x = (const float*)d_in[0];
  const int* ei = (const int*)d_in[1];
  const int* batch = (const int*)d_in[2];
  WP wp;
  const float* bvec[6];
  for (int i = 0; i < 6; ++i) {
    wp.p[i] = (const float*)d_in[3 + 2 * i];
    bvec[i] = (const float*)d_in[4 + 2 * i];
  }
  const float* linW = (const float*)d_in[15];
  const float* linb = (const float*)d_in[16];
  float* out = (float*)d_out;

  const int F = 128, H = 128, C = 32;
  const int N = in_sizes[0] / F;
  const int E = in_sizes[1] / 2;
  const int B = out_size / C;  // 512
  const int* src = ei;
  const int* dst = ei + E;

  // workspace carve-out (256B aligned slices)
  char* w = (char*)d_ws;
  auto alloc = [&](size_t bytes) -> char* {
    char* p = w;
    w += (bytes + 255) & ~(size_t)255;
    return p;
  };
  int* deg = (int*)alloc((size_t)N * 4);
  float* inv = (float*)alloc((size_t)N * 4);
  int* tmp = (int*)alloc((size_t)N * 4);
  int* sums = (int*)alloc(256 * 4);
  int* rp = (int*)alloc((size_t)(N + 1) * 4);
  int* cursor = (int*)alloc((size_t)N * 4);
  int* col = (int*)alloc((size_t)E * 4);
  int* gstart = (int*)alloc((size_t)(B + 1) * 4);
  _Float16* h16 = (_Float16*)alloc((size_t)N * H * 2);
  _Float16* hs16 = (_Float16*)alloc((size_t)N * H * 2);
  _Float16* wt16 = (_Float16*)alloc((size_t)6 * H * H * 2);
  float* pooled = (float*)alloc((size_t)B * H * 4);
  (void)n_in; (void)ws_size;

  hipMemsetAsync(deg, 0, (size_t)N * 4, stream);

  hist_i32<<<ceil_div(E, 256), 256, 0, stream>>>(dst, deg, E);
  inv_sqrt_deg<<<ceil_div(N, 256), 256, 0, stream>>>(deg, inv, N);

  int nchunk = ceil_div(N, 256);  // 196 for N=50000, fits scanB's 256 slots
  scanA<<<nchunk, 256, 0, stream>>>(deg, tmp, sums, N);
  scanB<<<1, 256, 0, stream>>>(sums, nchunk);
  scanC<<<nchunk, 256, 0, stream>>>(tmp, sums, rp, N);
  bsearch_starts<<<ceil_div(B + 1, 256), 256, 0, stream>>>(batch, gstart, N, B);

  hipMemcpyAsync(cursor, rp, (size_t)N * 4, hipMemcpyDeviceToDevice, stream);
  scatter_edges<<<ceil_div(E, 256), 256, 0, stream>>>(src, dst, cursor, col, E);

  f32_to_f16<<<ceil_div(N * F / 4, 256), 256, 0, stream>>>(x, h16, N * F);
  conv_weights<<<384, 256, 0, stream>>>(wp, wt16);

  for (int l = 0; l < 6; ++l) {
    gemm_mfma<<<ceil_div(N, 64), 256, 0, stream>>>(h16, wt16 + ((size_t)l << 14), inv,
                                                   hs16, N);
    aggregate<<<ceil_div(N, 4), 256, 0, stream>>>((const __half*)hs16, col, rp, inv,
                                                  bvec[l], (__half*)h16, N,
                                                  (l < 5) ? 1 : 0);
  }

  pool_mean<<<B, 128, 0, stream>>>((const __half*)h16, gstart, pooled);
  final_lin<<<ceil_div(B * C, 256), 256, 0, stream>>>(pooled, linW, linb, out, B * C);
}

// Round 6
// 496.714 us; speedup vs baseline: 1.3417x; 1.0773x over previous
//
#include <hip/hip_runtime.h>
#include <hip/hip_fp16.h>

// ---------------------------------------------------------------------------
// GCN 6-layer forward on MI355X — fp16 state + persistent register-B MFMA.
//   setup: deg/inv, row_ptr scan, counting-sort CSR, batch bsearch,
//          x -> fp16, W(6) -> fp16 transposed Wt[c][k]
//   per layer: hs16 = fp16(inv .* (h16 @ W))  [v_mfma_f32_16x16x32_f16,
//              B (32KB) held entirely in 128 VGPRs, wave loops over row-tiles]
//              h16  = fp16(act(inv .* (sum_e hs16[col[e]] + hs16[v]) + b))
//   pool (fp16 in, fp32 acc) -> final 128x32 linear (fp32)
// ---------------------------------------------------------------------------

static inline int ceil_div(int a, int b) { return (a + b - 1) / b; }

typedef _Float16 f16x8 __attribute__((ext_vector_type(8)));
typedef _Float16 f16x4 __attribute__((ext_vector_type(4)));
typedef float f32x4 __attribute__((ext_vector_type(4)));

// ---------------- setup kernels ----------------

__global__ __launch_bounds__(256) void hist_i32(const int* __restrict__ idx,
                                                int* __restrict__ cnt, int n) {
  int i = blockIdx.x * 256 + threadIdx.x;
  if (i < n) atomicAdd(&cnt[idx[i]], 1);
}

__global__ __launch_bounds__(256) void inv_sqrt_deg(const int* __restrict__ deg,
                                                    float* __restrict__ inv, int n) {
  int i = blockIdx.x * 256 + threadIdx.x;
  if (i < n) inv[i] = rsqrtf((float)(deg[i] + 1));  // +1 = self loop
}

__global__ __launch_bounds__(256) void scanA(const int* __restrict__ deg,
                                             int* __restrict__ tmp,
                                             int* __restrict__ sums, int n) {
  __shared__ int s[256];
  int t = threadIdx.x;
  int gid = blockIdx.x * 256 + t;
  s[t] = (gid < n) ? deg[gid] : 0;
  __syncthreads();
  for (int off = 1; off < 256; off <<= 1) {
    int add = (t >= off) ? s[t - off] : 0;
    __syncthreads();
    s[t] += add;
    __syncthreads();
  }
  if (gid < n) tmp[gid] = s[t];
  if (t == 255) sums[blockIdx.x] = s[255];
}

__global__ __launch_bounds__(256) void scanB(int* __restrict__ sums, int nchunk) {
  __shared__ int s[256];
  int t = threadIdx.x;
  s[t] = (t < nchunk) ? sums[t] : 0;
  __syncthreads();
  for (int off = 1; off < 256; off <<= 1) {
    int add = (t >= off) ? s[t - off] : 0;
    __syncthreads();
    s[t] += add;
    __syncthreads();
  }
  if (t < nchunk) sums[t] = s[t];
}

__global__ __launch_bounds__(256) void scanC(const int* __restrict__ tmp,
                                             const int* __restrict__ sums,
                                             int* __restrict__ rp, int n) {
  int gid = blockIdx.x * 256 + threadIdx.x;
  if (gid < n) {
    int off = (blockIdx.x > 0) ? sums[blockIdx.x - 1] : 0;
    rp[gid + 1] = tmp[gid] + off;
    if (gid == 0) rp[0] = 0;
  }
}

// gstart[g] = first i with batch[i] >= g  (batch sorted ascending)
__global__ __launch_bounds__(256) void bsearch_starts(const int* __restrict__ batch,
                                                      int* __restrict__ gstart,
                                                      int n, int B) {
  int g = blockIdx.x * 256 + threadIdx.x;
  if (g > B) return;
  int lo = 0, hi = n;
  while (lo < hi) {
    int mid = (lo + hi) >> 1;
    if (batch[mid] < g) lo = mid + 1; else hi = mid;
  }
  gstart[g] = lo;
}

__global__ __launch_bounds__(256) void scatter_edges(const int* __restrict__ src,
                                                     const int* __restrict__ dst,
                                                     int* __restrict__ cursor,
                                                     int* __restrict__ col, int E) {
  int i = blockIdx.x * 256 + threadIdx.x;
  if (i < E) {
    int d = dst[i];
    int pos = atomicAdd(&cursor[d], 1);
    col[pos] = src[i];
  }
}

// x (fp32) -> fp16, 4 elems/thread; n multiple of 4
__global__ __launch_bounds__(256) void f32_to_f16(const float* __restrict__ in,
                                                  _Float16* __restrict__ out, int n) {
  int i = (blockIdx.x * 256 + threadIdx.x) * 4;
  if (i < n) {
    float4 v = *(const float4*)&in[i];
    f16x4 o = {(_Float16)v.x, (_Float16)v.y, (_Float16)v.z, (_Float16)v.w};
    *(f16x4*)&out[i] = o;
  }
}

// 6 weights 128x128: wt[wi][c][k] = (fp16) W[wi][k][c]
struct WP { const float* p[6]; };
__global__ __launch_bounds__(256) void conv_weights(WP wp, _Float16* __restrict__ wt) {
  int wi = blockIdx.x >> 6;                       // 64 blocks per weight
  int e = (blockIdx.x & 63) * 256 + threadIdx.x;  // 0..16383
  int k = e >> 7, c = e & 127;
  wt[((size_t)wi << 14) + (size_t)c * 128 + k] = (_Float16)wp.p[wi][e];
}

// ---------------- per-layer kernels ----------------

// hs16[v][c] = fp16( inv[v] * sum_k h16[v][k] * W[k][c] )
// Persistent: 512 blocks x 4 waves; each wave loads ALL 32 B-fragments (32KB
// Wt) into 128 VGPRs ONCE, then loops over its share of 16-row tiles doing
// pure register MFMA. __launch_bounds__(256,2): 2 waves/SIMD at ~190 VGPR.
// Fragment layout: A lane l -> row (l&15), k = (l>>4)*8 + [0..8)
//                  B lane l -> col (l&15), k = (l>>4)*8 + [0..8)   (from Wt[c][k])
//                  C lane l -> col (l&15), row = (l>>4)*4 + reg    (HW-verified)
__global__ __launch_bounds__(256, 2) void gemm_mfma_p(const _Float16* __restrict__ A,
                                                      const _Float16* __restrict__ Wt,
                                                      const float* __restrict__ inv,
                                                      _Float16* __restrict__ out,
                                                      int nrows) {
  int lane = threadIdx.x & 63;
  int wv = threadIdx.x >> 6;  // 0..3
  int r = lane & 15, g = lane >> 4;

  // ---- load all B fragments once (static indices -> registers) ----
  f16x8 b[8][4];
  const _Float16* bp = Wt + (size_t)r * 128 + g * 8;
#pragma unroll
  for (int ct = 0; ct < 8; ++ct) {
    const _Float16* bt = bp + (size_t)ct * 16 * 128;
#pragma unroll
    for (int ks = 0; ks < 4; ++ks) b[ct][ks] = *(const f16x8*)(bt + ks * 32);
  }

  int tiles = (nrows + 15) >> 4;
  int chunk = (tiles + gridDim.x - 1) / (int)gridDim.x;
  int t0 = blockIdx.x * chunk;
  int t1 = t0 + chunk;
  if (t1 > tiles) t1 = tiles;

  for (int tt = t0 + wv; tt < t1; tt += 4) {
    int rowBase = tt * 16;

    int arow = rowBase + r;
    if (arow >= nrows) arow = nrows - 1;
    const _Float16* ap = A + (size_t)arow * 128 + g * 8;
    f16x8 a0 = *(const f16x8*)(ap + 0);
    f16x8 a1 = *(const f16x8*)(ap + 32);
    f16x8 a2 = *(const f16x8*)(ap + 64);
    f16x8 a3 = *(const f16x8*)(ap + 96);

    f32x4 acc[8];
#pragma unroll
    for (int ct = 0; ct < 8; ++ct) acc[ct] = (f32x4){0.f, 0.f, 0.f, 0.f};

#pragma unroll
    for (int ct = 0; ct < 8; ++ct) {
      acc[ct] = __builtin_amdgcn_mfma_f32_16x16x32_f16(a0, b[ct][0], acc[ct], 0, 0, 0);
      acc[ct] = __builtin_amdgcn_mfma_f32_16x16x32_f16(a1, b[ct][1], acc[ct], 0, 0, 0);
      acc[ct] = __builtin_amdgcn_mfma_f32_16x16x32_f16(a2, b[ct][2], acc[ct], 0, 0, 0);
      acc[ct] = __builtin_amdgcn_mfma_f32_16x16x32_f16(a3, b[ct][3], acc[ct], 0, 0, 0);
    }

    // epilogue: lane writes cols ct*16+r at rows rowBase + g*4 + j
#pragma unroll
    for (int j = 0; j < 4; ++j) {
      int row = rowBase + g * 4 + j;
      if (row < nrows) {
        float iv = inv[row];
#pragma unroll
        for (int ct = 0; ct < 8; ++ct)
          out[(size_t)row * 128 + ct * 16 + r] = (_Float16)(acc[ct][j] * iv);
      }
    }
  }
}

// h16out[v][:] = fp16(act(inv[v]*(sum_e hs16[col[e]][:] + hs16[v][:]) + b))
// one 64-lane wave per node, half2 per lane, 8-deep gather pipeline.
__global__ __launch_bounds__(256) void aggregate(const __half* __restrict__ hs,
                                                 const int* __restrict__ col,
                                                 const int* __restrict__ rp,
                                                 const float* __restrict__ inv,
                                                 const float* __restrict__ bias,
                                                 __half* __restrict__ out, int n,
                                                 int dorelu) {
  int node = blockIdx.x * 4 + (threadIdx.x >> 6);
  if (node >= n) return;
  int lane = threadIdx.x & 63;
  const __half2* h2 = (const __half2*)hs;

  int beg = rp[node], end = rp[node + 1];
  float2 self = __half22float2(h2[(size_t)node * 64 + lane]);
  float sx[8], sy[8];
  sx[0] = self.x; sy[0] = self.y;
#pragma unroll
  for (int i = 1; i < 8; ++i) { sx[i] = 0.f; sy[i] = 0.f; }

  int e = beg;
  for (; e + 8 <= end; e += 8) {
    int idx[8];
#pragma unroll
    for (int i = 0; i < 8; ++i) idx[i] = col[e + i];
    __half2 v[8];
#pragma unroll
    for (int i = 0; i < 8; ++i) v[i] = h2[(size_t)idx[i] * 64 + lane];
#pragma unroll
    for (int i = 0; i < 8; ++i) {
      float2 f = __half22float2(v[i]);
      sx[i] += f.x; sy[i] += f.y;
    }
  }
  if (e + 4 <= end) {
    int idx[4];
#pragma unroll
    for (int i = 0; i < 4; ++i) idx[i] = col[e + i];
    __half2 v[4];
#pragma unroll
    for (int i = 0; i < 4; ++i) v[i] = h2[(size_t)idx[i] * 64 + lane];
#pragma unroll
    for (int i = 0; i < 4; ++i) {
      float2 f = __half22float2(v[i]);
      sx[i] += f.x; sy[i] += f.y;
    }
    e += 4;
  }
  for (; e < end; ++e) {
    int s = col[e];
    float2 f = __half22float2(h2[(size_t)s * 64 + lane]);
    sx[0] += f.x; sy[0] += f.y;
  }

  float ax = (sx[0] + sx[1]) + (sx[2] + sx[3]);
  float bx = (sx[4] + sx[5]) + (sx[6] + sx[7]);
  float ay = (sy[0] + sy[1]) + (sy[2] + sy[3]);
  float by = (sy[4] + sy[5]) + (sy[6] + sy[7]);

  float iv = inv[node];
  float rx = iv * (ax + bx) + bias[lane * 2 + 0];
  float ry = iv * (ay + by) + bias[lane * 2 + 1];
  if (dorelu) { rx = fmaxf(rx, 0.f); ry = fmaxf(ry, 0.f); }
  ((__half2*)out)[(size_t)node * 64 + lane] = __floats2half2_rn(rx, ry);
}

// segment-mean pool: one block (128 threads) per graph, fp16 in, fp32 acc
__global__ __launch_bounds__(128) void pool_mean(const __half* __restrict__ h,
                                                 const int* __restrict__ gstart,
                                                 float* __restrict__ pooled) {
  int g = blockIdx.x;
  int c = threadIdx.x;
  int s = gstart[g], e = gstart[g + 1];
  float acc = 0.f;
  for (int v = s; v < e; ++v) acc += __half2float(h[(size_t)v * 128 + c]);
  int cnt = e - s;
  pooled[(size_t)g * 128 + c] = acc / (float)(cnt > 0 ? cnt : 1);
}

// out[g][c] = sum_k pooled[g][k] * lin_W[k][c] + lin_b[c]   (512x32 outputs)
__global__ __launch_bounds__(256) void final_lin(const float* __restrict__ pooled,
                                                 const float* __restrict__ lw,
                                                 const float* __restrict__ lb,
                                                 float* __restrict__ out, int total) {
  int idx = blockIdx.x * 256 + threadIdx.x;
  if (idx >= total) return;
  int g = idx >> 5;
  int c = idx & 31;
  float s = 0.f;
#pragma unroll 8
  for (int k = 0; k < 128; ++k) s += pooled[(size_t)g * 128 + k] * lw[k * 32 + c];
  out[idx] = s + lb[c];
}

// ---------------- launch ----------------

extern "C" void kernel_launch(void* const* d_in, const int* in_sizes, int n_in,
                              void* d_out, int out_size, void* d_ws, size_t ws_size,
                              hipStream_t stream) {
  const float* x = (const float*)d_in[0];
  const int* ei = (const int*)d_in[1];
  const int* batch = (const int*)d_in[2];
  WP wp;
  const float* bvec[6];
  for (int i = 0; i < 6; ++i) {
    wp.p[i] = (const float*)d_in[3 + 2 * i];
    bvec[i] = (const float*)d_in[4 + 2 * i];
  }
  const float* linW = (const float*)d_in[15];
  const float* linb = (const float*)d_in[16];
  float* out = (float*)d_out;

  const int F = 128, H = 128, C = 32;
  const int N = in_sizes[0] / F;
  const int E = in_sizes[1] / 2;
  const int B = out_size / C;  // 512
  const int* src = ei;
  const int* dst = ei + E;

  // workspace carve-out (256B aligned slices)
  char* w = (char*)d_ws;
  auto alloc = [&](size_t bytes) -> char* {
    char* p = w;
    w += (bytes + 255) & ~(size_t)255;
    return p;
  };
  int* deg = (int*)alloc((size_t)N * 4);
  float* inv = (float*)alloc((size_t)N * 4);
  int* tmp = (int*)alloc((size_t)N * 4);
  int* sums = (int*)alloc(256 * 4);
  int* rp = (int*)alloc((size_t)(N + 1) * 4);
  int* cursor = (int*)alloc((size_t)N * 4);
  int* col = (int*)alloc((size_t)E * 4);
  int* gstart = (int*)alloc((size_t)(B + 1) * 4);
  _Float16* h16 = (_Float16*)alloc((size_t)N * H * 2);
  _Float16* hs16 = (_Float16*)alloc((size_t)N * H * 2);
  _Float16* wt16 = (_Float16*)alloc((size_t)6 * H * H * 2);
  float* pooled = (float*)alloc((size_t)B * H * 4);
  (void)n_in; (void)ws_size;

  hipMemsetAsync(deg, 0, (size_t)N * 4, stream);

  hist_i32<<<ceil_div(E, 256), 256, 0, stream>>>(dst, deg, E);
  inv_sqrt_deg<<<ceil_div(N, 256), 256, 0, stream>>>(deg, inv, N);

  int nchunk = ceil_div(N, 256);  // 196 for N=50000, fits scanB's 256 slots
  scanA<<<nchunk, 256, 0, stream>>>(deg, tmp, sums, N);
  scanB<<<1, 256, 0, stream>>>(sums, nchunk);
  scanC<<<nchunk, 256, 0, stream>>>(tmp, sums, rp, N);
  bsearch_starts<<<ceil_div(B + 1, 256), 256, 0, stream>>>(batch, gstart, N, B);

  hipMemcpyAsync(cursor, rp, (size_t)N * 4, hipMemcpyDeviceToDevice, stream);
  scatter_edges<<<ceil_div(E, 256), 256, 0, stream>>>(src, dst, cursor, col, E);

  f32_to_f16<<<ceil_div(N * F / 4, 256), 256, 0, stream>>>(x, h16, N * F);
  conv_weights<<<384, 256, 0, stream>>>(wp, wt16);

  for (int l = 0; l < 6; ++l) {
    gemm_mfma_p<<<512, 256, 0, stream>>>(h16, wt16 + ((size_t)l << 14), inv, hs16, N);
    aggregate<<<ceil_div(N, 4), 256, 0, stream>>>((const __half*)hs16, col, rp, inv,
                                                  bvec[l], (__half*)h16, N,
                                                  (l < 5) ? 1 : 0);
  }

  pool_mean<<<B, 128, 0, stream>>>((const __half*)h16, gstart, pooled);
  final_lin<<<ceil_div(B * C, 256), 256, 0, stream>>>(pooled, linW, linb, out, B * C);
}

// Round 7
// 493.319 us; speedup vs baseline: 1.3509x; 1.0069x over previous
//
#include <hip/hip_runtime.h>
#include <hip/hip_fp16.h>

// ---------------------------------------------------------------------------
// GCN 6-layer forward on MI355X — fp16 state + persistent register-B MFMA
// with swapped operands (coalesced epilogue).
//   setup: deg/inv, row_ptr scan (+cursor), counting-sort CSR,
//          fused {x->fp16, W->fp16 Wt[c][k], batch bsearch}
//   per layer: hs16 = fp16(inv .* (h16 @ W))  [mfma(Wt_frag, h_frag): D[col][node],
//              lane = one node, 4 consecutive cols/tile -> 8B stores]
//              h16  = fp16(act(inv .* (sum_e hs16[col[e]] + hs16[v]) + b))
//   pool (fp16 in, fp32 acc) -> final 128x32 linear (fp32)
// ---------------------------------------------------------------------------

static inline int ceil_div(int a, int b) { return (a + b - 1) / b; }

typedef _Float16 f16x8 __attribute__((ext_vector_type(8)));
typedef _Float16 f16x4 __attribute__((ext_vector_type(4)));
typedef float f32x4 __attribute__((ext_vector_type(4)));

// ---------------- setup kernels ----------------

__global__ __launch_bounds__(256) void hist_i32(const int* __restrict__ idx,
                                                int* __restrict__ cnt, int n) {
  int i = blockIdx.x * 256 + threadIdx.x;
  if (i < n) atomicAdd(&cnt[idx[i]], 1);
}

// inclusive scan chunk + inv = rsqrt(deg+1) folded in
__global__ __launch_bounds__(256) void scanA(const int* __restrict__ deg,
                                             int* __restrict__ tmp,
                                             int* __restrict__ sums,
                                             float* __restrict__ inv, int n) {
  __shared__ int s[256];
  int t = threadIdx.x;
  int gid = blockIdx.x * 256 + t;
  int d = (gid < n) ? deg[gid] : 0;
  if (gid < n) inv[gid] = rsqrtf((float)(d + 1));  // +1 = self loop
  s[t] = d;
  __syncthreads();
  for (int off = 1; off < 256; off <<= 1) {
    int add = (t >= off) ? s[t - off] : 0;
    __syncthreads();
    s[t] += add;
    __syncthreads();
  }
  if (gid < n) tmp[gid] = s[t];
  if (t == 255) sums[blockIdx.x] = s[255];
}

__global__ __launch_bounds__(256) void scanB(int* __restrict__ sums, int nchunk) {
  __shared__ int s[256];
  int t = threadIdx.x;
  s[t] = (t < nchunk) ? sums[t] : 0;
  __syncthreads();
  for (int off = 1; off < 256; off <<= 1) {
    int add = (t >= off) ? s[t - off] : 0;
    __syncthreads();
    s[t] += add;
    __syncthreads();
  }
  if (t < nchunk) sums[t] = s[t];
}

// rp[gid+1] = global inclusive; cursor[gid] = rp[gid] (exclusive) folded in
__global__ __launch_bounds__(256) void scanC(const int* __restrict__ tmp,
                                             const int* __restrict__ sums,
                                             const int* __restrict__ deg,
                                             int* __restrict__ rp,
                                             int* __restrict__ cursor, int n) {
  int gid = blockIdx.x * 256 + threadIdx.x;
  if (gid < n) {
    int off = (blockIdx.x > 0) ? sums[blockIdx.x - 1] : 0;
    int incl = tmp[gid] + off;
    rp[gid + 1] = incl;
    cursor[gid] = incl - deg[gid];
    if (gid == 0) rp[0] = 0;
  }
}

__global__ __launch_bounds__(256) void scatter_edges(const int* __restrict__ src,
                                                     const int* __restrict__ dst,
                                                     int* __restrict__ cursor,
                                                     int* __restrict__ col, int E) {
  int i = blockIdx.x * 256 + threadIdx.x;
  if (i < E) {
    int d = dst[i];
    int pos = atomicAdd(&cursor[d], 1);
    col[pos] = src[i];
  }
}

// fused: [0, nbF) x->fp16 | [nbF, nbF+384) W->Wt fp16 | rest: batch bsearch
struct WP { const float* p[6]; };
__global__ __launch_bounds__(256) void setup_fuse(const float* __restrict__ x,
                                                  _Float16* __restrict__ h16,
                                                  WP wp, _Float16* __restrict__ wt,
                                                  const int* __restrict__ batch,
                                                  int* __restrict__ gstart,
                                                  int nelem, int nodes, int B,
                                                  int nbF) {
  int blk = blockIdx.x;
  if (blk < nbF) {
    int i = (blk * 256 + threadIdx.x) * 4;
    if (i < nelem) {
      float4 v = *(const float4*)&x[i];
      f16x4 o = {(_Float16)v.x, (_Float16)v.y, (_Float16)v.z, (_Float16)v.w};
      *(f16x4*)&h16[i] = o;
    }
  } else if (blk < nbF + 384) {
    int b2 = blk - nbF;
    int wi = b2 >> 6;                            // 64 blocks per weight
    int e = (b2 & 63) * 256 + threadIdx.x;       // 0..16383
    int k = e >> 7, c = e & 127;
    wt[((size_t)wi << 14) + (size_t)c * 128 + k] = (_Float16)wp.p[wi][e];
  } else {
    int g = (blk - nbF - 384) * 256 + threadIdx.x;
    if (g <= B) {
      int lo = 0, hi = nodes;
      while (lo < hi) {
        int mid = (lo + hi) >> 1;
        if (batch[mid] < g) lo = mid + 1; else hi = mid;
      }
      gstart[g] = lo;
    }
  }
}

// ---------------- per-layer kernels ----------------

// hs16[v][c] = fp16( inv[v] * sum_k h16[v][k] * W[k][c] )
// Persistent: 512 blocks x 4 waves; each wave holds all 32 Wt fragments
// (32KB) in 128 VGPRs, grid-strides over 16-row tiles.
// SWAPPED operands: acc[ct] = mfma(Wt_frag[ct], h_frag) -> D[col][node]:
//   lane l: node = rowBase + (l&15); cols = ct*16 + (l>>4)*4 + [0..4)
// -> epilogue: 1 inv load + 8 x 8B stores per lane (coalesced in 4-col runs).
__global__ __launch_bounds__(256, 2) void gemm_mfma_p(const _Float16* __restrict__ A,
                                                      const _Float16* __restrict__ Wt,
                                                      const float* __restrict__ inv,
                                                      _Float16* __restrict__ out,
                                                      int nrows) {
  int lane = threadIdx.x & 63;
  int wv = threadIdx.x >> 6;  // 0..3
  int r = lane & 15, g = lane >> 4;

  // ---- load all Wt fragments once (static indices -> registers) ----
  f16x8 b[8][4];
  const _Float16* bp = Wt + (size_t)r * 128 + g * 8;
#pragma unroll
  for (int ct = 0; ct < 8; ++ct) {
    const _Float16* bt = bp + (size_t)ct * 16 * 128;
#pragma unroll
    for (int ks = 0; ks < 4; ++ks) b[ct][ks] = *(const f16x8*)(bt + ks * 32);
  }

  int tiles = (nrows + 15) >> 4;
  int nwaves = (int)gridDim.x * 4;
  for (int tt = blockIdx.x * 4 + wv; tt < tiles; tt += nwaves) {
    int rowBase = tt * 16;

    int arow = rowBase + r;
    if (arow >= nrows) arow = nrows - 1;
    const _Float16* ap = A + (size_t)arow * 128 + g * 8;
    f16x8 a0 = *(const f16x8*)(ap + 0);
    f16x8 a1 = *(const f16x8*)(ap + 32);
    f16x8 a2 = *(const f16x8*)(ap + 64);
    f16x8 a3 = *(const f16x8*)(ap + 96);

    f32x4 acc[8];
#pragma unroll
    for (int ct = 0; ct < 8; ++ct) acc[ct] = (f32x4){0.f, 0.f, 0.f, 0.f};

#pragma unroll
    for (int ct = 0; ct < 8; ++ct) {
      acc[ct] = __builtin_amdgcn_mfma_f32_16x16x32_f16(b[ct][0], a0, acc[ct], 0, 0, 0);
      acc[ct] = __builtin_amdgcn_mfma_f32_16x16x32_f16(b[ct][1], a1, acc[ct], 0, 0, 0);
      acc[ct] = __builtin_amdgcn_mfma_f32_16x16x32_f16(b[ct][2], a2, acc[ct], 0, 0, 0);
      acc[ct] = __builtin_amdgcn_mfma_f32_16x16x32_f16(b[ct][3], a3, acc[ct], 0, 0, 0);
    }

    // epilogue: this lane owns node rowBase+r, cols ct*16 + g*4 + [0..4)
    int node = rowBase + r;
    if (node < nrows) {
      float iv = inv[node];
      _Float16* op = out + (size_t)node * 128 + g * 4;
#pragma unroll
      for (int ct = 0; ct < 8; ++ct) {
        __half2 lo = __floats2half2_rn(acc[ct][0] * iv, acc[ct][1] * iv);
        __half2 hi = __floats2half2_rn(acc[ct][2] * iv, acc[ct][3] * iv);
        uint2 sv;
        sv.x = *(unsigned*)&lo;
        sv.y = *(unsigned*)&hi;
        *(uint2*)(op + ct * 16) = sv;
      }
    }
  }
}

// h16out[v][:] = fp16(act(inv[v]*(sum_e hs16[col[e]][:] + hs16[v][:]) + b))
// one 64-lane wave per node, half2 per lane, 8-deep gather pipeline.
__global__ __launch_bounds__(256) void aggregate(const __half* __restrict__ hs,
                                                 const int* __restrict__ col,
                                                 const int* __restrict__ rp,
                                                 const float* __restrict__ inv,
                                                 const float* __restrict__ bias,
                                                 __half* __restrict__ out, int n,
                                                 int dorelu) {
  int node = blockIdx.x * 4 + (threadIdx.x >> 6);
  if (node >= n) return;
  int lane = threadIdx.x & 63;
  const __half2* h2 = (const __half2*)hs;

  int beg = rp[node], end = rp[node + 1];
  float2 self = __half22float2(h2[(size_t)node * 64 + lane]);
  float sx[8], sy[8];
  sx[0] = self.x; sy[0] = self.y;
#pragma unroll
  for (int i = 1; i < 8; ++i) { sx[i] = 0.f; sy[i] = 0.f; }

  int e = beg;
  for (; e + 8 <= end; e += 8) {
    int idx[8];
#pragma unroll
    for (int i = 0; i < 8; ++i) idx[i] = col[e + i];
    __half2 v[8];
#pragma unroll
    for (int i = 0; i < 8; ++i) v[i] = h2[(size_t)idx[i] * 64 + lane];
#pragma unroll
    for (int i = 0; i < 8; ++i) {
      float2 f = __half22float2(v[i]);
      sx[i] += f.x; sy[i] += f.y;
    }
  }
  if (e + 4 <= end) {
    int idx[4];
#pragma unroll
    for (int i = 0; i < 4; ++i) idx[i] = col[e + i];
    __half2 v[4];
#pragma unroll
    for (int i = 0; i < 4; ++i) v[i] = h2[(size_t)idx[i] * 64 + lane];
#pragma unroll
    for (int i = 0; i < 4; ++i) {
      float2 f = __half22float2(v[i]);
      sx[i] += f.x; sy[i] += f.y;
    }
    e += 4;
  }
  for (; e < end; ++e) {
    int s = col[e];
    float2 f = __half22float2(h2[(size_t)s * 64 + lane]);
    sx[0] += f.x; sy[0] += f.y;
  }

  float ax = (sx[0] + sx[1]) + (sx[2] + sx[3]);
  float bx = (sx[4] + sx[5]) + (sx[6] + sx[7]);
  float ay = (sy[0] + sy[1]) + (sy[2] + sy[3]);
  float by = (sy[4] + sy[5]) + (sy[6] + sy[7]);

  float iv = inv[node];
  float rx = iv * (ax + bx) + bias[lane * 2 + 0];
  float ry = iv * (ay + by) + bias[lane * 2 + 1];
  if (dorelu) { rx = fmaxf(rx, 0.f); ry = fmaxf(ry, 0.f); }
  ((__half2*)out)[(size_t)node * 64 + lane] = __floats2half2_rn(rx, ry);
}

// segment-mean pool: one block (128 threads) per graph, fp16 in, fp32 acc
__global__ __launch_bounds__(128) void pool_mean(const __half* __restrict__ h,
                                                 const int* __restrict__ gstart,
                                                 float* __restrict__ pooled) {
  int g = blockIdx.x;
  int c = threadIdx.x;
  int s = gstart[g], e = gstart[g + 1];
  float acc = 0.f;
  for (int v = s; v < e; ++v) acc += __half2float(h[(size_t)v * 128 + c]);
  int cnt = e - s;
  pooled[(size_t)g * 128 + c] = acc / (float)(cnt > 0 ? cnt : 1);
}

// out[g][c] = sum_k pooled[g][k] * lin_W[k][c] + lin_b[c]   (512x32 outputs)
__global__ __launch_bounds__(256) void final_lin(const float* __restrict__ pooled,
                                                 const float* __restrict__ lw,
                                                 const float* __restrict__ lb,
                                                 float* __restrict__ out, int total) {
  int idx = blockIdx.x * 256 + threadIdx.x;
  if (idx >= total) return;
  int g = idx >> 5;
  int c = idx & 31;
  float s = 0.f;
#pragma unroll 8
  for (int k = 0; k < 128; ++k) s += pooled[(size_t)g * 128 + k] * lw[k * 32 + c];
  out[idx] = s + lb[c];
}

// ---------------- launch ----------------

extern "C" void kernel_launch(void* const* d_in, const int* in_sizes, int n_in,
                              void* d_out, int out_size, void* d_ws, size_t ws_size,
                              hipStream_t stream) {
  const float* x = (const float*)d_in[0];
  const int* ei = (const int*)d_in[1];
  const int* batch = (const int*)d_in[2];
  WP wp;
  const float* bvec[6];
  for (int i = 0; i < 6; ++i) {
    wp.p[i] = (const float*)d_in[3 + 2 * i];
    bvec[i] = (const float*)d_in[4 + 2 * i];
  }
  const float* linW = (const float*)d_in[15];
  const float* linb = (const float*)d_in[16];
  float* out = (float*)d_out;

  const int F = 128, H = 128, C = 32;
  const int N = in_sizes[0] / F;
  const int E = in_sizes[1] / 2;
  const int B = out_size / C;  // 512
  const int* src = ei;
  const int* dst = ei + E;

  // workspace carve-out (256B aligned slices)
  char* w = (char*)d_ws;
  auto alloc = [&](size_t bytes) -> char* {
    char* p = w;
    w += (bytes + 255) & ~(size_t)255;
    return p;
  };
  int* deg = (int*)alloc((size_t)N * 4);
  float* inv = (float*)alloc((size_t)N * 4);
  int* tmp = (int*)alloc((size_t)N * 4);
  int* sums = (int*)alloc(256 * 4);
  int* rp = (int*)alloc((size_t)(N + 1) * 4);
  int* cursor = (int*)alloc((size_t)N * 4);
  int* col = (int*)alloc((size_t)E * 4);
  int* gstart = (int*)alloc((size_t)(B + 1) * 4);
  _Float16* h16 = (_Float16*)alloc((size_t)N * H * 2);
  _Float16* hs16 = (_Float16*)alloc((size_t)N * H * 2);
  _Float16* wt16 = (_Float16*)alloc((size_t)6 * H * H * 2);
  float* pooled = (float*)alloc((size_t)B * H * 4);
  (void)n_in; (void)ws_size;

  hipMemsetAsync(deg, 0, (size_t)N * 4, stream);

  hist_i32<<<ceil_div(E, 256), 256, 0, stream>>>(dst, deg, E);

  int nchunk = ceil_div(N, 256);  // 196 for N=50000, fits scanB's 256 slots
  scanA<<<nchunk, 256, 0, stream>>>(deg, tmp, sums, inv, N);
  scanB<<<1, 256, 0, stream>>>(sums, nchunk);
  scanC<<<nchunk, 256, 0, stream>>>(tmp, sums, deg, rp, cursor, N);

  int nbF = ceil_div(N * F / 4, 256);
  int nbBS = ceil_div(B + 1, 256);
  setup_fuse<<<nbF + 384 + nbBS, 256, 0, stream>>>(x, h16, wp, wt16, batch, gstart,
                                                   N * F, N, B, nbF);

  scatter_edges<<<ceil_div(E, 256), 256, 0, stream>>>(src, dst, cursor, col, E);

  for (int l = 0; l < 6; ++l) {
    gemm_mfma_p<<<512, 256, 0, stream>>>(h16, wt16 + ((size_t)l << 14), inv, hs16, N);
    aggregate<<<ceil_div(N, 4), 256, 0, stream>>>((const __half*)hs16, col, rp, inv,
                                                  bvec[l], (__half*)h16, N,
                                                  (l < 5) ? 1 : 0);
  }

  pool_mean<<<B, 128, 0, stream>>>((const __half*)h16, gstart, pooled);
  final_lin<<<ceil_div(B * C, 256), 256, 0, stream>>>(pooled, linW, linb, out, B * C);
}

// Round 9
// 484.685 us; speedup vs baseline: 1.3750x; 1.0178x over previous
//
#include <hip/hip_runtime.h>
#include <hip/hip_fp16.h>

// ---------------------------------------------------------------------------
// GCN 6-layer forward on MI355X — fp16 state + persistent register-B MFMA
// + wide-load aggregate (16B/lane, 4 edges/wave in parallel).
//   fp8 messages FAILED R8 (absmax 1.9e-3 > thr 3.9e-5): fp16 floor it is.
//   setup: deg/inv, row_ptr scan (+cursor), counting-sort CSR,
//          fused {x->fp16, W->fp16 Wt[c][k], batch bsearch}
//   per layer: hs16 = fp16(inv .* (h16 @ W))  [mfma(Wt,h): D[col][node]]
//              h16  = fp16(act(inv .* (sum_e hs16[col[e]] + hs16[v]) + b))
//   pool (fp16 in, fp32 acc) -> final 128x32 linear (fp32)
// ---------------------------------------------------------------------------

static inline int ceil_div(int a, int b) { return (a + b - 1) / b; }

typedef _Float16 f16x8 __attribute__((ext_vector_type(8)));
typedef _Float16 f16x4 __attribute__((ext_vector_type(4)));
typedef float f32x4 __attribute__((ext_vector_type(4)));

// ---------------- setup kernels ----------------

__global__ __launch_bounds__(256) void hist_i32(const int* __restrict__ idx,
                                                int* __restrict__ cnt, int n) {
  int i = blockIdx.x * 256 + threadIdx.x;
  if (i < n) atomicAdd(&cnt[idx[i]], 1);
}

// inclusive scan chunk + inv = rsqrt(deg+1) folded in
__global__ __launch_bounds__(256) void scanA(const int* __restrict__ deg,
                                             int* __restrict__ tmp,
                                             int* __restrict__ sums,
                                             float* __restrict__ inv, int n) {
  __shared__ int s[256];
  int t = threadIdx.x;
  int gid = blockIdx.x * 256 + t;
  int d = (gid < n) ? deg[gid] : 0;
  if (gid < n) inv[gid] = rsqrtf((float)(d + 1));  // +1 = self loop
  s[t] = d;
  __syncthreads();
  for (int off = 1; off < 256; off <<= 1) {
    int add = (t >= off) ? s[t - off] : 0;
    __syncthreads();
    s[t] += add;
    __syncthreads();
  }
  if (gid < n) tmp[gid] = s[t];
  if (t == 255) sums[blockIdx.x] = s[255];
}

__global__ __launch_bounds__(256) void scanB(int* __restrict__ sums, int nchunk) {
  __shared__ int s[256];
  int t = threadIdx.x;
  s[t] = (t < nchunk) ? sums[t] : 0;
  __syncthreads();
  for (int off = 1; off < 256; off <<= 1) {
    int add = (t >= off) ? s[t - off] : 0;
    __syncthreads();
    s[t] += add;
    __syncthreads();
  }
  if (t < nchunk) sums[t] = s[t];
}

// rp[gid+1] = global inclusive; cursor[gid] = rp[gid] (exclusive) folded in
__global__ __launch_bounds__(256) void scanC(const int* __restrict__ tmp,
                                             const int* __restrict__ sums,
                                             const int* __restrict__ deg,
                                             int* __restrict__ rp,
                                             int* __restrict__ cursor, int n) {
  int gid = blockIdx.x * 256 + threadIdx.x;
  if (gid < n) {
    int off = (blockIdx.x > 0) ? sums[blockIdx.x - 1] : 0;
    int incl = tmp[gid] + off;
    rp[gid + 1] = incl;
    cursor[gid] = incl - deg[gid];
    if (gid == 0) rp[0] = 0;
  }
}

__global__ __launch_bounds__(256) void scatter_edges(const int* __restrict__ src,
                                                     const int* __restrict__ dst,
                                                     int* __restrict__ cursor,
                                                     int* __restrict__ col, int E) {
  int i = blockIdx.x * 256 + threadIdx.x;
  if (i < E) {
    int d = dst[i];
    int pos = atomicAdd(&cursor[d], 1);
    col[pos] = src[i];
  }
}

// fused: [0, nbF) x->fp16 | [nbF, nbF+384) W->Wt fp16 | rest: batch bsearch
struct WP { const float* p[6]; };
__global__ __launch_bounds__(256) void setup_fuse(const float* __restrict__ x,
                                                  _Float16* __restrict__ h16,
                                                  WP wp, _Float16* __restrict__ wt,
                                                  const int* __restrict__ batch,
                                                  int* __restrict__ gstart,
                                                  int nelem, int nodes, int B,
                                                  int nbF) {
  int blk = blockIdx.x;
  if (blk < nbF) {
    int i = (blk * 256 + threadIdx.x) * 4;
    if (i < nelem) {
      float4 v = *(const float4*)&x[i];
      f16x4 o = {(_Float16)v.x, (_Float16)v.y, (_Float16)v.z, (_Float16)v.w};
      *(f16x4*)&h16[i] = o;
    }
  } else if (blk < nbF + 384) {
    int b2 = blk - nbF;
    int wi = b2 >> 6;                            // 64 blocks per weight
    int e = (b2 & 63) * 256 + threadIdx.x;       // 0..16383
    int k = e >> 7, c = e & 127;
    wt[((size_t)wi << 14) + (size_t)c * 128 + k] = (_Float16)wp.p[wi][e];
  } else {
    int g = (blk - nbF - 384) * 256 + threadIdx.x;
    if (g <= B) {
      int lo = 0, hi = nodes;
      while (lo < hi) {
        int mid = (lo + hi) >> 1;
        if (batch[mid] < g) lo = mid + 1; else hi = mid;
      }
      gstart[g] = lo;
    }
  }
}

// ---------------- per-layer kernels ----------------

// hs16[v][c] = fp16( inv[v] * sum_k h16[v][k] * W[k][c] )
// Persistent: 512 blocks x 4 waves; each wave holds all 32 Wt fragments
// (32KB) in 128 VGPRs, grid-strides over 16-row tiles.
// SWAPPED operands: acc[ct] = mfma(Wt_frag[ct], h_frag) -> D[col][node]:
//   lane l: node = rowBase + (l&15); cols = ct*16 + (l>>4)*4 + [0..4)
// -> epilogue: 1 inv load + 8 x 8B stores per lane.
__global__ __launch_bounds__(256, 2) void gemm_mfma_p(const _Float16* __restrict__ A,
                                                      const _Float16* __restrict__ Wt,
                                                      const float* __restrict__ inv,
                                                      _Float16* __restrict__ out,
                                                      int nrows) {
  int lane = threadIdx.x & 63;
  int wv = threadIdx.x >> 6;  // 0..3
  int r = lane & 15, g = lane >> 4;

  // ---- load all Wt fragments once (static indices -> registers) ----
  f16x8 b[8][4];
  const _Float16* bp = Wt + (size_t)r * 128 + g * 8;
#pragma unroll
  for (int ct = 0; ct < 8; ++ct) {
    const _Float16* bt = bp + (size_t)ct * 16 * 128;
#pragma unroll
    for (int ks = 0; ks < 4; ++ks) b[ct][ks] = *(const f16x8*)(bt + ks * 32);
  }

  int tiles = (nrows + 15) >> 4;
  int nwaves = (int)gridDim.x * 4;
  for (int tt = blockIdx.x * 4 + wv; tt < tiles; tt += nwaves) {
    int rowBase = tt * 16;

    int arow = rowBase + r;
    if (arow >= nrows) arow = nrows - 1;
    const _Float16* ap = A + (size_t)arow * 128 + g * 8;
    f16x8 a0 = *(const f16x8*)(ap + 0);
    f16x8 a1 = *(const f16x8*)(ap + 32);
    f16x8 a2 = *(const f16x8*)(ap + 64);
    f16x8 a3 = *(const f16x8*)(ap + 96);

    f32x4 acc[8];
#pragma unroll
    for (int ct = 0; ct < 8; ++ct) acc[ct] = (f32x4){0.f, 0.f, 0.f, 0.f};

#pragma unroll
    for (int ct = 0; ct < 8; ++ct) {
      acc[ct] = __builtin_amdgcn_mfma_f32_16x16x32_f16(b[ct][0], a0, acc[ct], 0, 0, 0);
      acc[ct] = __builtin_amdgcn_mfma_f32_16x16x32_f16(b[ct][1], a1, acc[ct], 0, 0, 0);
      acc[ct] = __builtin_amdgcn_mfma_f32_16x16x32_f16(b[ct][2], a2, acc[ct], 0, 0, 0);
      acc[ct] = __builtin_amdgcn_mfma_f32_16x16x32_f16(b[ct][3], a3, acc[ct], 0, 0, 0);
    }

    // epilogue: this lane owns node rowBase+r, cols ct*16 + g*4 + [0..4)
    int node = rowBase + r;
    if (node < nrows) {
      float iv = inv[node];
      _Float16* op = out + (size_t)node * 128 + g * 4;
#pragma unroll
      for (int ct = 0; ct < 8; ++ct) {
        __half2 lo = __floats2half2_rn(acc[ct][0] * iv, acc[ct][1] * iv);
        __half2 hi = __floats2half2_rn(acc[ct][2] * iv, acc[ct][3] * iv);
        uint2 sv;
        sv.x = *(unsigned*)&lo;
        sv.y = *(unsigned*)&hi;
        *(uint2*)(op + ct * 16) = sv;
      }
    }
  }
}

// h16out[v][:] = fp16(act(inv[v]*(sum_e hs16[col[e]][:] + hs16[v][:]) + b))
// one wave per node; 4 lane-groups of 16 process 4 edges concurrently.
// Each lane loads 16B (f16x8) of a 256B row -> 16 vmem instrs/edge (was 64).
// Cross-group reduce: shfl_xor 16/32, once per node.
__global__ __launch_bounds__(256) void aggregate(const _Float16* __restrict__ hs,
                                                 const int* __restrict__ col,
                                                 const int* __restrict__ rp,
                                                 const float* __restrict__ inv,
                                                 const float* __restrict__ bias,
                                                 _Float16* __restrict__ out, int n,
                                                 int dorelu) {
  int node = blockIdx.x * 4 + (threadIdx.x >> 6);
  if (node >= n) return;
  int lane = threadIdx.x & 63;
  int sub = lane >> 4;   // edge slot 0..3
  int cl = lane & 15;    // col group: 8 fp16 at cl*8

  int beg = rp[node], end = rp[node + 1];
  float acc[8];
#pragma unroll
  for (int j = 0; j < 8; ++j) acc[j] = 0.f;

  if (sub == 0) {  // self row once
    f16x8 v = *(const f16x8*)(hs + (size_t)node * 128 + cl * 8);
#pragma unroll
    for (int j = 0; j < 8; ++j) acc[j] += (float)v[j];
  }

  int e = beg;
  for (; e + 16 <= end; e += 16) {  // 4 indep 16B loads in flight per lane
    int i0 = col[e + sub];
    int i1 = col[e + 4 + sub];
    int i2 = col[e + 8 + sub];
    int i3 = col[e + 12 + sub];
    f16x8 v0 = *(const f16x8*)(hs + (size_t)i0 * 128 + cl * 8);
    f16x8 v1 = *(const f16x8*)(hs + (size_t)i1 * 128 + cl * 8);
    f16x8 v2 = *(const f16x8*)(hs + (size_t)i2 * 128 + cl * 8);
    f16x8 v3 = *(const f16x8*)(hs + (size_t)i3 * 128 + cl * 8);
#pragma unroll
    for (int j = 0; j < 8; ++j)
      acc[j] += ((float)v0[j] + (float)v1[j]) + ((float)v2[j] + (float)v3[j]);
  }
  if (e + 8 <= end) {
    int i0 = col[e + sub];
    int i1 = col[e + 4 + sub];
    f16x8 v0 = *(const f16x8*)(hs + (size_t)i0 * 128 + cl * 8);
    f16x8 v1 = *(const f16x8*)(hs + (size_t)i1 * 128 + cl * 8);
#pragma unroll
    for (int j = 0; j < 8; ++j) acc[j] += (float)v0[j] + (float)v1[j];
    e += 8;
  }
  if (e + 4 <= end) {
    int i0 = col[e + sub];
    f16x8 v0 = *(const f16x8*)(hs + (size_t)i0 * 128 + cl * 8);
#pragma unroll
    for (int j = 0; j < 8; ++j) acc[j] += (float)v0[j];
    e += 4;
  }
  int rem = end - e;  // 0..3
  if (sub < rem) {
    int i0 = col[e + sub];
    f16x8 v0 = *(const f16x8*)(hs + (size_t)i0 * 128 + cl * 8);
#pragma unroll
    for (int j = 0; j < 8; ++j) acc[j] += (float)v0[j];
  }

  // reduce the 4 edge-slots (lane bits 4,5)
#pragma unroll
  for (int j = 0; j < 8; ++j) {
    acc[j] += __shfl_xor(acc[j], 16, 64);
    acc[j] += __shfl_xor(acc[j], 32, 64);
  }

  if (sub == 0) {
    float iv = inv[node];
    float4 b0 = *(const float4*)&bias[cl * 8];
    float4 b1 = *(const float4*)&bias[cl * 8 + 4];
    float rb[8] = {b0.x, b0.y, b0.z, b0.w, b1.x, b1.y, b1.z, b1.w};
    f16x8 o;
#pragma unroll
    for (int j = 0; j < 8; ++j) {
      float r = iv * acc[j] + rb[j];
      if (dorelu) r = fmaxf(r, 0.f);
      o[j] = (_Float16)r;
    }
    *(f16x8*)(out + (size_t)node * 128 + cl * 8) = o;
  }
}

// segment-mean pool: one block (128 threads) per graph, fp16 in, fp32 acc
__global__ __launch_bounds__(128) void pool_mean(const __half* __restrict__ h,
                                                 const int* __restrict__ gstart,
                                                 float* __restrict__ pooled) {
  int g = blockIdx.x;
  int c = threadIdx.x;
  int s = gstart[g], e = gstart[g + 1];
  float acc = 0.f;
  for (int v = s; v < e; ++v) acc += __half2float(h[(size_t)v * 128 + c]);
  int cnt = e - s;
  pooled[(size_t)g * 128 + c] = acc / (float)(cnt > 0 ? cnt : 1);
}

// out[g][c] = sum_k pooled[g][k] * lin_W[k][c] + lin_b[c]   (512x32 outputs)
__global__ __launch_bounds__(256) void final_lin(const float* __restrict__ pooled,
                                                 const float* __restrict__ lw,
                                                 const float* __restrict__ lb,
                                                 float* __restrict__ out, int total) {
  int idx = blockIdx.x * 256 + threadIdx.x;
  if (idx >= total) return;
  int g = idx >> 5;
  int c = idx & 31;
  float s = 0.f;
#pragma unroll 8
  for (int k = 0; k < 128; ++k) s += pooled[(size_t)g * 128 + k] * lw[k * 32 + c];
  out[idx] = s + lb[c];
}

// ---------------- launch ----------------

extern "C" void kernel_launch(void* const* d_in, const int* in_sizes, int n_in,
                              void* d_out, int out_size, void* d_ws, size_t ws_size,
                              hipStream_t stream) {
  const float* x = (const float*)d_in[0];
  const int* ei = (const int*)d_in[1];
  const int* batch = (const int*)d_in[2];
  WP wp;
  const float* bvec[6];
  for (int i = 0; i < 6; ++i) {
    wp.p[i] = (const float*)d_in[3 + 2 * i];
    bvec[i] = (const float*)d_in[4 + 2 * i];
  }
  const float* linW = (const float*)d_in[15];
  const float* linb = (const float*)d_in[16];
  float* out = (float*)d_out;

  const int F = 128, H = 128, C = 32;
  const int N = in_sizes[0] / F;
  const int E = in_sizes[1] / 2;
  const int B = out_size / C;  // 512
  const int* src = ei;
  const int* dst = ei + E;

  // workspace carve-out (256B aligned slices)
  char* w = (char*)d_ws;
  auto alloc = [&](size_t bytes) -> char* {
    char* p = w;
    w += (bytes + 255) & ~(size_t)255;
    return p;
  };
  int* deg = (int*)alloc((size_t)N * 4);
  float* inv = (float*)alloc((size_t)N * 4);
  int* tmp = (int*)alloc((size_t)N * 4);
  int* sums = (int*)alloc(256 * 4);
  int* rp = (int*)alloc((size_t)(N + 1) * 4);
  int* cursor = (int*)alloc((size_t)N * 4);
  int* col = (int*)alloc((size_t)E * 4);
  int* gstart = (int*)alloc((size_t)(B + 1) * 4);
  _Float16* h16 = (_Float16*)alloc((size_t)N * H * 2);
  _Float16* hs16 = (_Float16*)alloc((size_t)N * H * 2);
  _Float16* wt16 = (_Float16*)alloc((size_t)6 * H * H * 2);
  float* pooled = (float*)alloc((size_t)B * H * 4);
  (void)n_in; (void)ws_size;

  hipMemsetAsync(deg, 0, (size_t)N * 4, stream);

  hist_i32<<<ceil_div(E, 256), 256, 0, stream>>>(dst, deg, E);

  int nchunk = ceil_div(N, 256);  // 196 for N=50000, fits scanB's 256 slots
  scanA<<<nchunk, 256, 0, stream>>>(deg, tmp, sums, inv, N);
  scanB<<<1, 256, 0, stream>>>(sums, nchunk);
  scanC<<<nchunk, 256, 0, stream>>>(tmp, sums, deg, rp, cursor, N);

  int nbF = ceil_div(N * F / 4, 256);
  int nbBS = ceil_div(B + 1, 256);
  setup_fuse<<<nbF + 384 + nbBS, 256, 0, stream>>>(x, h16, wp, wt16, batch, gstart,
                                                   N * F, N, B, nbF);

  scatter_edges<<<ceil_div(E, 256), 256, 0, stream>>>(src, dst, cursor, col, E);

  for (int l = 0; l < 6; ++l) {
    gemm_mfma_p<<<512, 256, 0, stream>>>(h16, wt16 + ((size_t)l << 14), inv, hs16, N);
    aggregate<<<ceil_div(N, 4), 256, 0, stream>>>(hs16, col, rp, inv, bvec[l],
                                                  h16, N, (l < 5) ? 1 : 0);
  }

  pool_mean<<<B, 128, 0, stream>>>((const __half*)h16, gstart, pooled);
  final_lin<<<ceil_div(B * C, 256), 256, 0, stream>>>(pooled, linW, linb, out, B * C);
}